// Round 1
// baseline (158.178 us; speedup 1.0000x reference)
//
#include <hip/hip_runtime.h>
#include <hip/hip_bf16.h>
#include <math.h>

#define B_ 16
#define P_ 16384
#define T_ 128
#define C_ 80
#define IOU_THR 0.5f

__device__ __forceinline__ float smooth_l1(float d) {
    float ad = fabsf(d);
    return (ad < 1.0f) ? 0.5f * d * d : ad - 0.5f;
}

// One block = 256 preds of one batch image.
// grid = B_ * (P_/256) = 1024 blocks
__global__ __launch_bounds__(256) void det_loss_main(
        const float* __restrict__ pred_bboxes,   // (B,P,4)
        const float* __restrict__ true_bboxes,   // (B,T,4)
        float* __restrict__ ws)                  // ws[0]=sum_elem, ws[1]=n_matched
{
    const int blocks_per_b = P_ / 256;           // 64
    const int b    = blockIdx.x / blocks_per_b;
    const int pblk = blockIdx.x % blocks_per_b;
    const int tid  = threadIdx.x;

    __shared__ float4 tb[T_];                    // 2 KB true boxes for this batch
    if (tid < T_) {
        tb[tid] = ((const float4*)true_bboxes)[b * T_ + tid];
    }
    __syncthreads();

    const int p = pblk * 256 + tid;
    const float4 pb = ((const float4*)pred_bboxes)[(size_t)b * P_ + p];
    const float pa = (pb.z - pb.x) * (pb.w - pb.y);

    // max/argmax IoU over T true boxes; strict > keeps FIRST max (matches jnp.argmax)
    float best = -1.0f;
    int   bidx = 0;
    #pragma unroll 4
    for (int t = 0; t < T_; ++t) {
        const float4 t4 = tb[t];                 // same-address broadcast: conflict-free
        const float x1 = fmaxf(pb.x, t4.x);
        const float y1 = fmaxf(pb.y, t4.y);
        const float x2 = fminf(pb.z, t4.z);
        const float y2 = fminf(pb.w, t4.w);
        const float iw = fmaxf(x2 - x1, 0.0f);
        const float ih = fmaxf(y2 - y1, 0.0f);
        const float inter = iw * ih;
        const float ta = (t4.z - t4.x) * (t4.w - t4.y);
        const float iou = inter / (pa + ta - inter);
        if (iou > best) { best = iou; bidx = t; }
    }

    float contrib = 0.0f, cnt = 0.0f;
    if (best > IOU_THR) {
        const float4 t4 = tb[bidx];
        contrib = smooth_l1(pb.x - t4.x) + smooth_l1(pb.y - t4.y)
                + smooth_l1(pb.z - t4.z) + smooth_l1(pb.w - t4.w);
        cnt = 1.0f;
    }

    // wave64 shuffle reduce, then cross-wave LDS reduce, one atomic pair per block
    #pragma unroll
    for (int off = 32; off > 0; off >>= 1) {
        contrib += __shfl_down(contrib, off, 64);
        cnt     += __shfl_down(cnt,     off, 64);
    }
    __shared__ float sc[4], sn[4];
    const int wave = tid >> 6, lane = tid & 63;
    if (lane == 0) { sc[wave] = contrib; sn[wave] = cnt; }
    __syncthreads();
    if (tid == 0) {
        atomicAdd(&ws[0], sc[0] + sc[1] + sc[2] + sc[3]);
        atomicAdd(&ws[1], sn[0] + sn[1] + sn[2] + sn[3]);
    }
}

// Single small block: classification loss over (16 rows x 80 classes) + final combine
__global__ __launch_bounds__(64) void det_loss_final(
        const float* __restrict__ pred_classes,  // (B,P,C) — only [:,0,:] used
        const int*   __restrict__ true_labels,   // (B,T)   — only [:,0] used
        const float* __restrict__ ws,
        float* __restrict__ out)
{
    const int tid = threadIdx.x;
    __shared__ float rowloss[B_];
    if (tid < B_) {
        const float* row = pred_classes + (size_t)tid * P_ * C_;  // [b, 0, :]
        const int lab = true_labels[tid * T_];                    // [b, 0]
        float m = -INFINITY;
        for (int c = 0; c < C_; ++c) m = fmaxf(m, row[c]);
        float s = 0.0f;
        for (int c = 0; c < C_; ++c) s += expf(row[c] - m);
        rowloss[tid] = -(row[lab] - m - logf(s));
    }
    __syncthreads();
    if (tid == 0) {
        float cl = 0.0f;
        for (int b = 0; b < B_; ++b) cl += rowloss[b];
        cl *= (1.0f / B_);
        const float bbox = ws[0] / fmaxf(4.0f * ws[1], 1.0f);
        out[0] = bbox + cl;
    }
}

extern "C" void kernel_launch(void* const* d_in, const int* in_sizes, int n_in,
                              void* d_out, int out_size, void* d_ws, size_t ws_size,
                              hipStream_t stream) {
    const float* pred_bboxes  = (const float*)d_in[0];
    const float* pred_classes = (const float*)d_in[1];
    const float* true_bboxes  = (const float*)d_in[2];
    const int*   true_labels  = (const int*)d_in[3];
    float* out = (float*)d_out;
    float* ws  = (float*)d_ws;

    // ws is poisoned to 0xAA before every timed call — zero the 2 accumulators
    hipMemsetAsync(ws, 0, 2 * sizeof(float), stream);

    det_loss_main<<<B_ * (P_ / 256), 256, 0, stream>>>(pred_bboxes, true_bboxes, ws);
    det_loss_final<<<1, 64, 0, stream>>>(pred_classes, true_labels, ws, out);
}

// Round 2
// 133.470 us; speedup vs baseline: 1.1851x; 1.1851x over previous
//
#include <hip/hip_runtime.h>
#include <hip/hip_bf16.h>
#include <math.h>

#define B_ 16
#define P_ 16384
#define T_ 128
#define C_ 80

// ws layout: ws[0..511] = per-block bbox-loss partials, ws[512..1023] = per-block match counts

__device__ __forceinline__ float smooth_l1(float d) {
    float ad = fabsf(d);
    return (ad < 1.0f) ? 0.5f * d * d : ad - 0.5f;
}

// One block = 512 preds (2 per thread) of one batch image. grid = B_ * 32 = 512
__global__ __launch_bounds__(256) void det_loss_main(
        const float* __restrict__ pred_bboxes,   // (B,P,4)
        const float* __restrict__ true_bboxes,   // (B,T,4)
        float* __restrict__ ws)
{
    const int blocks_per_b = P_ / 512;           // 32
    const int b    = blockIdx.x / blocks_per_b;
    const int pblk = blockIdx.x % blocks_per_b;
    const int tid  = threadIdx.x;

    __shared__ float4 tb[T_];
    if (tid < T_) tb[tid] = ((const float4*)true_bboxes)[b * T_ + tid];
    __syncthreads();

    const float4* pbase = (const float4*)pred_bboxes + (size_t)b * P_ + pblk * 512;
    const float4 pA = pbase[tid];
    const float4 pB = pbase[tid + 256];
    const float paA = (pA.z - pA.x) * (pA.w - pA.y);
    const float paB = (pB.z - pB.x) * (pB.w - pB.y);

    // running argmax of iou without division:
    //   iou_t > iou_best  <=>  inter_t * u_best > inter_best * u_t   (unions > 0)
    float biA = 0.0f, buA = 1.0f; int bxA = 0;
    float biB = 0.0f, buB = 1.0f; int bxB = 0;

    #pragma unroll 8
    for (int t = 0; t < T_; ++t) {
        const float4 t4 = tb[t];                         // same-address broadcast
        const float ta = (t4.z - t4.x) * (t4.w - t4.y);  // uniform per t, shared

        {   // pred A
            const float iw = fmaxf(fminf(pA.z, t4.z) - fmaxf(pA.x, t4.x), 0.0f);
            const float ih = fmaxf(fminf(pA.w, t4.w) - fmaxf(pA.y, t4.y), 0.0f);
            const float inter = iw * ih;
            const float u = (paA + ta) - inter;
            const bool upd = inter * buA > biA * u;      // strict > keeps FIRST max
            biA = upd ? inter : biA;
            buA = upd ? u : buA;
            bxA = upd ? t : bxA;
        }
        {   // pred B
            const float iw = fmaxf(fminf(pB.z, t4.z) - fmaxf(pB.x, t4.x), 0.0f);
            const float ih = fmaxf(fminf(pB.w, t4.w) - fmaxf(pB.y, t4.y), 0.0f);
            const float inter = iw * ih;
            const float u = (paB + ta) - inter;
            const bool upd = inter * buB > biB * u;
            biB = upd ? inter : biB;
            buB = upd ? u : buB;
            bxB = upd ? t : bxB;
        }
    }

    float contrib = 0.0f, cnt = 0.0f;
    if (2.0f * biA > buA) {                              // iou > 0.5
        const float4 m4 = tb[bxA];
        contrib += smooth_l1(pA.x - m4.x) + smooth_l1(pA.y - m4.y)
                 + smooth_l1(pA.z - m4.z) + smooth_l1(pA.w - m4.w);
        cnt += 1.0f;
    }
    if (2.0f * biB > buB) {
        const float4 m4 = tb[bxB];
        contrib += smooth_l1(pB.x - m4.x) + smooth_l1(pB.y - m4.y)
                 + smooth_l1(pB.z - m4.z) + smooth_l1(pB.w - m4.w);
        cnt += 1.0f;
    }

    #pragma unroll
    for (int off = 32; off > 0; off >>= 1) {
        contrib += __shfl_down(contrib, off, 64);
        cnt     += __shfl_down(cnt,     off, 64);
    }
    __shared__ float sc[4], sn[4];
    const int wave = tid >> 6, lane = tid & 63;
    if (lane == 0) { sc[wave] = contrib; sn[wave] = cnt; }
    __syncthreads();
    if (tid == 0) {
        ws[blockIdx.x]       = sc[0] + sc[1] + sc[2] + sc[3];
        ws[512 + blockIdx.x] = sn[0] + sn[1] + sn[2] + sn[3];
    }
}

// One block, 1024 threads: wave w = log-softmax of row w (16 rows x 80 classes),
// then reduce the 512+512 block partials and combine.
__global__ __launch_bounds__(1024) void det_loss_final(
        const float* __restrict__ pred_classes,  // (B,P,C) — only [:,0,:] used
        const int*   __restrict__ true_labels,   // (B,T)   — only [:,0] used
        const float* __restrict__ ws,
        float* __restrict__ out)
{
    const int tid = threadIdx.x;
    const int wave = tid >> 6, lane = tid & 63;

    __shared__ float rowloss[B_];
    __shared__ float wc[16], wn[16];

    // phase 1: one wave per batch row
    const float* row = pred_classes + (size_t)wave * P_ * C_;   // [b,0,:]
    const float v0 = row[lane];
    const float v1 = (lane < C_ - 64) ? row[lane + 64] : -INFINITY;
    float m = fmaxf(v0, v1);
    #pragma unroll
    for (int off = 32; off > 0; off >>= 1) m = fmaxf(m, __shfl_xor(m, off, 64));
    float s = expf(v0 - m) + ((lane < C_ - 64) ? expf(v1 - m) : 0.0f);
    #pragma unroll
    for (int off = 32; off > 0; off >>= 1) s += __shfl_xor(s, off, 64);
    if (lane == 0) {
        const int lab = true_labels[wave * T_];
        rowloss[wave] = -(row[lab] - m - logf(s));
    }

    // phase 2: reduce block partials (threads 0..127 carry data, rest contribute 0)
    float sc = 0.0f, sn = 0.0f;
    if (tid < 128) {
        const float4 c4 = ((const float4*)ws)[tid];
        const float4 n4 = ((const float4*)(ws + 512))[tid];
        sc = c4.x + c4.y + c4.z + c4.w;
        sn = n4.x + n4.y + n4.z + n4.w;
    }
    #pragma unroll
    for (int off = 32; off > 0; off >>= 1) {
        sc += __shfl_down(sc, off, 64);
        sn += __shfl_down(sn, off, 64);
    }
    if (lane == 0) { wc[wave] = sc; wn[wave] = sn; }
    __syncthreads();

    if (tid == 0) {
        float C = 0.0f, N = 0.0f, cl = 0.0f;
        #pragma unroll
        for (int w = 0; w < 16; ++w) { C += wc[w]; N += wn[w]; cl += rowloss[w]; }
        out[0] = C / fmaxf(4.0f * N, 1.0f) + cl * (1.0f / B_);
    }
}

extern "C" void kernel_launch(void* const* d_in, const int* in_sizes, int n_in,
                              void* d_out, int out_size, void* d_ws, size_t ws_size,
                              hipStream_t stream) {
    const float* pred_bboxes  = (const float*)d_in[0];
    const float* pred_classes = (const float*)d_in[1];
    const float* true_bboxes  = (const float*)d_in[2];
    const int*   true_labels  = (const int*)d_in[3];
    float* out = (float*)d_out;
    float* ws  = (float*)d_ws;

    det_loss_main<<<B_ * (P_ / 512), 256, 0, stream>>>(pred_bboxes, true_bboxes, ws);
    det_loss_final<<<1, 1024, 0, stream>>>(pred_classes, true_labels, ws, out);
}